// Round 3
// baseline (122.591 us; speedup 1.0000x reference)
//
#include <hip/hip_runtime.h>

#define NUSR 8192
#define HDIM 256

typedef __attribute__((ext_vector_type(8))) __bf16 bf16x8;
typedef __attribute__((ext_vector_type(4))) float f32x4;

union frag_u { bf16x8 v; unsigned short u[8]; unsigned int d[4]; };

// f32 -> bf16 RNE
__device__ __forceinline__ unsigned int f2bf(float f) {
  unsigned u = __builtin_bit_cast(unsigned, f);
  u += 0x7FFFu + ((u >> 16) & 1u);
  return u >> 16;
}
__device__ __forceinline__ unsigned int f2bf2(float lo, float hi) {
  return f2bf(lo) | (f2bf(hi) << 16);
}
__device__ __forceinline__ float sigmoidf_fast(float x) {
  float e = __builtin_amdgcn_exp2f(x * -1.44269504088896340736f);
  return __builtin_amdgcn_rcpf(1.0f + e);
}

// PX layout (proj in MFMA-B fragment order), ushort offsets:
//   PX[(col>>4)*4096 + (k>>5)*512 + ((k>>3)&3)*128 + (col&15)*8 + (k&7)]
// -> B-frag for (col16 ct, kb) = 16B at PX + ct*4096 + kb*512 + lane*8 (lane-linear).

// ---------------------------------------------------------------------------
// k1_fused: ONE launch doing both prep stages concurrently.
//   blocks 0..255   : proj -> PX (32 yb rows each; W frags converted inline).
//   blocks 256..511 : ya -> yabf bf16 conversion.
//   block 511       : additionally zeroes svec.
// ---------------------------------------------------------------------------
__global__ __launch_bounds__(256) void k1_fused(
    const float* __restrict__ ya, const float* __restrict__ yb,
    const float* __restrict__ W, const float* __restrict__ bvec,
    unsigned short* __restrict__ yabf, unsigned short* __restrict__ PX,
    float* __restrict__ svec)
{
  const int b   = blockIdx.x;   // 0..511
  const int tid = threadIdx.x;

  if (b < 256) {
    // ---- proj part ----
    const int lane = tid & 63;
    const int w    = tid >> 6;   // st-quarter 0..3
    const int q    = lane >> 4;
    const int i    = lane & 15;

    frag_u B[2][8]; // 2 row-groups x 8 k-blocks of yb, bf16 B-frags
#pragma unroll
    for (int g = 0; g < 2; ++g) {
      const float* ybrow = yb + (size_t)(b * 32 + g * 16 + i) * HDIM;
#pragma unroll
      for (int kb = 0; kb < 8; ++kb) {
        float4 v0 = *(const float4*)&ybrow[kb * 32 + q * 8];
        float4 v1 = *(const float4*)&ybrow[kb * 32 + q * 8 + 4];
        B[g][kb].d[0] = f2bf2(v0.x, v0.y); B[g][kb].d[1] = f2bf2(v0.z, v0.w);
        B[g][kb].d[2] = f2bf2(v1.x, v1.y); B[g][kb].d[3] = f2bf2(v1.z, v1.w);
      }
    }

#pragma unroll
    for (int t = 0; t < 4; ++t) {
      const int st = w * 4 + t;
      f32x4 acc[2] = {{0.f,0.f,0.f,0.f},{0.f,0.f,0.f,0.f}};
#pragma unroll
      for (int kb = 0; kb < 8; ++kb) {
        const float* wr = W + (size_t)(st * 16 + i) * HDIM + kb * 32 + q * 8;
        float4 w0 = *(const float4*)wr;
        float4 w1 = *(const float4*)(wr + 4);
        frag_u Af;
        Af.d[0] = f2bf2(w0.x, w0.y); Af.d[1] = f2bf2(w0.z, w0.w);
        Af.d[2] = f2bf2(w1.x, w1.y); Af.d[3] = f2bf2(w1.z, w1.w);
#pragma unroll
        for (int g = 0; g < 2; ++g)
          acc[g] = __builtin_amdgcn_mfma_f32_16x16x32_bf16(Af.v, B[g][kb].v, acc[g], 0, 0, 0);
      }
      float4 bias = *(const float4*)&bvec[st * 16 + q * 4];
#pragma unroll
      for (int g = 0; g < 2; ++g) {
        const int jg = b * 2 + g;
        unsigned v0 = f2bf2(acc[g][0] + bias.x, acc[g][1] + bias.y);
        unsigned v1 = f2bf2(acc[g][2] + bias.z, acc[g][3] + bias.w);
        size_t off = (size_t)jg * 4096 + (size_t)(st >> 1) * 512
                   + (size_t)(((st & 1) << 1) | (q >> 1)) * 128 + i * 8 + ((q & 1) * 4);
        *(uint2*)(PX + off) = make_uint2(v0, v1);
      }
    }
  } else {
    // ---- ya -> bf16 conversion part (256 blocks, 262144 uint4 chunks) ----
    const int id = (b - 256) * 256 + tid;  // 0..65535
    const float4* src = (const float4*)ya;
    uint4* dst = (uint4*)yabf;
#pragma unroll
    for (int u = 0; u < 4; ++u) {
      int d = id + u * 65536;
      float4 a = src[d * 2];
      float4 c = src[d * 2 + 1];
      uint4 o = { f2bf2(a.x, a.y), f2bf2(a.z, a.w),
                  f2bf2(c.x, c.y), f2bf2(c.z, c.w) };
      dst[d] = o;
    }
    if (b == 511) {
      float4 z = {0.f, 0.f, 0.f, 0.f};
      float4* sv = (float4*)svec;
#pragma unroll
      for (int u = 0; u < 8; ++u) sv[u * 256 + tid] = z;
    }
  }
}

// ---------------------------------------------------------------------------
// k2: s[i] += sum_j sigmoid( ya[i] . proj[j] )
// T3/T4 pipelined LDS version: cross-wave sharing (1x PX traffic, 128 MB L2
// total) with a 3-deep LDS buffer ring and COUNTED vmcnt instead of the
// __syncthreads vmcnt(0) drain:
//   per tile: s_waitcnt vmcnt(4) [tile t ready, t+1 still in flight]
//             s_barrier          [everyone done reading t-1 -> its buf is free]
//             stage t+2          [4 global_load_lds/thread]
//             compute t          [setprio(1) around the MFMA cluster]
// vmcnt never drains to 0 in the main loop. Race-free: writer of t+2 touches
// buf (t+2)%3, readers hold t (t%3) and t+1; the barrier orders the overwrite
// of t-1's buffer after all reads of t-1.
// ---------------------------------------------------------------------------
__global__ __launch_bounds__(256, 2) void k2_score(
    const unsigned short* __restrict__ yabf, const unsigned short* __restrict__ PX,
    float* __restrict__ svec)
{
  __shared__ __align__(16) unsigned short bs[3][8192]; // 3 x 16 KB ring
  const int tid  = threadIdx.x;
  const int lane = tid & 63;
  const int w    = tid >> 6;
  const int quad = lane >> 4;
  const int l15  = lane & 15;

  // XCD swizzle: bid = k*8 + xcd -> XCD 'xcd' sees only col-slices {2xcd, 2xcd+1}
  const int bid = blockIdx.x;          // 0..511
  const int xcd = bid & 7;
  const int k   = bid >> 3;            // 0..63
  const int by  = xcd * 2 + (k >> 5);  // 0..15
  const int bx  = k & 31;              // 0..31

  const int rbase = bx * 256 + w * 64;
  const int cg16  = by * 32;           // col16-group base (512 cols)

  // A-frags: 64 ya rows per wave, direct bf16 16B loads (32 dwordx4/thread)
  frag_u A[4][8];
#pragma unroll
  for (int g = 0; g < 4; ++g) {
    const unsigned short* src = yabf + (size_t)(rbase + g * 16 + l15) * HDIM;
#pragma unroll
    for (int kb = 0; kb < 8; ++kb)
      A[g][kb].v = *(const bf16x8*)&src[kb * 32 + quad * 8];
  }

  const unsigned short* psrc = PX + (size_t)cg16 * 4096; // this block's 256 KB

  float rs[4][4] = {{0.f,0.f,0.f,0.f},{0.f,0.f,0.f,0.f},
                    {0.f,0.f,0.f,0.f},{0.f,0.f,0.f,0.f}};

#define STAGE(B, T)                                                          \
  do {                                                                       \
    const unsigned short* _src = psrc + (size_t)(T) * 8192;                  \
    unsigned short* _dst = &bs[(B)][0];                                      \
    _Pragma("unroll")                                                        \
    for (int p = 0; p < 4; ++p) {                                            \
      int c = p * 256 + tid;                                                 \
      __builtin_amdgcn_global_load_lds(                                      \
          (const __attribute__((address_space(1))) unsigned int*)(const void*)(_src + c * 8), \
          (__attribute__((address_space(3))) unsigned int*)(void*)(_dst + c * 8), \
          16, 0, 0);                                                         \
    }                                                                        \
  } while (0)

  // prologue: tiles 0 and 1 in flight (8 outstanding stage loads/thread)
  STAGE(0, 0);
  STAGE(1, 1);

  int cb = 0, sb = 2;
  for (int t = 0; t < 16; ++t) {       // 16 tiles x 32 cols = 512 cols
    if (t < 15)
      asm volatile("s_waitcnt vmcnt(4)" ::: "memory");  // tile t landed; t+1 flying
    else
      asm volatile("s_waitcnt vmcnt(0)" ::: "memory");  // last tile
    asm volatile("s_barrier" ::: "memory");             // no auto vmcnt(0) drain
    if (t < 14)
      STAGE(sb, t + 2);                // overlaps the whole compute phase below

    const unsigned short* buf = &bs[cb][0];
#pragma unroll
    for (int tt = 0; tt < 2; ++tt) {
      f32x4 acc[4] = {{0.f,0.f,0.f,0.f},{0.f,0.f,0.f,0.f},
                      {0.f,0.f,0.f,0.f},{0.f,0.f,0.f,0.f}};
      __builtin_amdgcn_s_setprio(1);
#pragma unroll
      for (int kb = 0; kb < 8; ++kb) {
        bf16x8 bfrag = *(const bf16x8*)&buf[(tt * 512 + kb * 64 + lane) * 8];
#pragma unroll
        for (int g = 0; g < 4; ++g)
          acc[g] = __builtin_amdgcn_mfma_f32_16x16x32_bf16(A[g][kb].v, bfrag, acc[g], 0, 0, 0);
      }
      __builtin_amdgcn_s_setprio(0);
#pragma unroll
      for (int g = 0; g < 4; ++g)
#pragma unroll
        for (int r = 0; r < 4; ++r)
          rs[g][r] += sigmoidf_fast(acc[g][r]);
    }
    cb = (cb == 2) ? 0 : cb + 1;
    sb = (sb == 2) ? 0 : sb + 1;
  }
#undef STAGE

  // reduce over the 16 col-lanes within each quad group
#pragma unroll
  for (int off = 1; off < 16; off <<= 1)
#pragma unroll
    for (int g = 0; g < 4; ++g)
#pragma unroll
      for (int r = 0; r < 4; ++r)
        rs[g][r] += __shfl_xor(rs[g][r], off, 64);

  if (l15 == 0) {
#pragma unroll
    for (int g = 0; g < 4; ++g)
#pragma unroll
      for (int r = 0; r < 4; ++r)
        atomicAdd(&svec[rbase + g * 16 + quad * 4 + r], rs[g][r]);
  }
}

// ---------------------------------------------------------------------------
// k3: out[i][k] = s[i] / 256
// ---------------------------------------------------------------------------
__global__ __launch_bounds__(256) void k3_bcast(
    const float* __restrict__ svec, float* __restrict__ out)
{
  int idx = blockIdx.x * 256 + threadIdx.x;
  int row = idx >> 6;
  float v = svec[row] * (1.0f / 256.0f);
  float4 o = {v, v, v, v};
  ((float4*)out)[idx] = o;
}

extern "C" void kernel_launch(void* const* d_in, const int* in_sizes, int n_in,
                              void* d_out, int out_size, void* d_ws, size_t ws_size,
                              hipStream_t stream) {
  (void)in_sizes; (void)n_in; (void)out_size;
  const float* ya = (const float*)d_in[0];
  const float* yb = (const float*)d_in[1];
  const float* W  = (const float*)d_in[2];
  const float* bv = (const float*)d_in[3];
  float* out = (float*)d_out;

  char* ws = (char*)d_ws;
  unsigned short *PX, *yabf;
  float* svec;
  const size_t need = (8ull << 20) + (32ull << 10);
  if (ws_size >= need) {
    PX   = (unsigned short*)ws;
    yabf = (unsigned short*)(ws + (4 << 20));
    svec = (float*)(ws + (8 << 20));
  } else {
    PX   = (unsigned short*)d_out;                 // aliases out; k3 rewrites all
    yabf = (unsigned short*)((char*)d_out + (4 << 20));
    svec = (float*)ws;
  }

  k1_fused<<<512, 256, 0, stream>>>(ya, yb, W, bv, yabf, PX, svec);
  k2_score<<<512, 256, 0, stream>>>(yabf, PX, svec);
  k3_bcast<<<2048, 256, 0, stream>>>(svec, out);
}

// Round 4
// 122.301 us; speedup vs baseline: 1.0024x; 1.0024x over previous
//
#include <hip/hip_runtime.h>

#define NUSR 8192
#define HDIM 256

typedef __attribute__((ext_vector_type(8))) __bf16 bf16x8;
typedef __attribute__((ext_vector_type(4))) float f32x4;

union frag_u { bf16x8 v; unsigned short u[8]; unsigned int d[4]; };

// f32 -> bf16 RNE
__device__ __forceinline__ unsigned int f2bf(float f) {
  unsigned u = __builtin_bit_cast(unsigned, f);
  u += 0x7FFFu + ((u >> 16) & 1u);
  return u >> 16;
}
__device__ __forceinline__ unsigned int f2bf2(float lo, float hi) {
  return f2bf(lo) | (f2bf(hi) << 16);
}
__device__ __forceinline__ float sigmoidf_fast(float x) {
  float e = __builtin_amdgcn_exp2f(x * -1.44269504088896340736f);
  return __builtin_amdgcn_rcpf(1.0f + e);
}

// PX layout (proj in MFMA-B fragment order), ushort offsets:
//   PX[(col>>4)*4096 + (k>>5)*512 + ((k>>3)&3)*128 + (col&15)*8 + (k&7)]
// -> B-frag for (col16 ct, kb) = 16B at PX + ct*4096 + kb*512 + lane*8 (lane-linear).

// ---------------------------------------------------------------------------
// k1_fused: ONE launch doing both prep stages concurrently.
//   blocks 0..255   : proj -> PX (32 yb rows each; W frags converted inline).
//   blocks 256..511 : ya -> yabf bf16 conversion.
//   block 511       : additionally zeroes svec.
// ---------------------------------------------------------------------------
__global__ __launch_bounds__(256) void k1_fused(
    const float* __restrict__ ya, const float* __restrict__ yb,
    const float* __restrict__ W, const float* __restrict__ bvec,
    unsigned short* __restrict__ yabf, unsigned short* __restrict__ PX,
    float* __restrict__ svec)
{
  const int b   = blockIdx.x;   // 0..511
  const int tid = threadIdx.x;

  if (b < 256) {
    // ---- proj part ----
    const int lane = tid & 63;
    const int w    = tid >> 6;   // st-quarter 0..3
    const int q    = lane >> 4;
    const int i    = lane & 15;

    frag_u B[2][8]; // 2 row-groups x 8 k-blocks of yb, bf16 B-frags
#pragma unroll
    for (int g = 0; g < 2; ++g) {
      const float* ybrow = yb + (size_t)(b * 32 + g * 16 + i) * HDIM;
#pragma unroll
      for (int kb = 0; kb < 8; ++kb) {
        float4 v0 = *(const float4*)&ybrow[kb * 32 + q * 8];
        float4 v1 = *(const float4*)&ybrow[kb * 32 + q * 8 + 4];
        B[g][kb].d[0] = f2bf2(v0.x, v0.y); B[g][kb].d[1] = f2bf2(v0.z, v0.w);
        B[g][kb].d[2] = f2bf2(v1.x, v1.y); B[g][kb].d[3] = f2bf2(v1.z, v1.w);
      }
    }

#pragma unroll
    for (int t = 0; t < 4; ++t) {
      const int st = w * 4 + t;
      f32x4 acc[2] = {{0.f,0.f,0.f,0.f},{0.f,0.f,0.f,0.f}};
#pragma unroll
      for (int kb = 0; kb < 8; ++kb) {
        const float* wr = W + (size_t)(st * 16 + i) * HDIM + kb * 32 + q * 8;
        float4 w0 = *(const float4*)wr;
        float4 w1 = *(const float4*)(wr + 4);
        frag_u Af;
        Af.d[0] = f2bf2(w0.x, w0.y); Af.d[1] = f2bf2(w0.z, w0.w);
        Af.d[2] = f2bf2(w1.x, w1.y); Af.d[3] = f2bf2(w1.z, w1.w);
#pragma unroll
        for (int g = 0; g < 2; ++g)
          acc[g] = __builtin_amdgcn_mfma_f32_16x16x32_bf16(Af.v, B[g][kb].v, acc[g], 0, 0, 0);
      }
      float4 bias = *(const float4*)&bvec[st * 16 + q * 4];
#pragma unroll
      for (int g = 0; g < 2; ++g) {
        const int jg = b * 2 + g;
        unsigned v0 = f2bf2(acc[g][0] + bias.x, acc[g][1] + bias.y);
        unsigned v1 = f2bf2(acc[g][2] + bias.z, acc[g][3] + bias.w);
        size_t off = (size_t)jg * 4096 + (size_t)(st >> 1) * 512
                   + (size_t)(((st & 1) << 1) | (q >> 1)) * 128 + i * 8 + ((q & 1) * 4);
        *(uint2*)(PX + off) = make_uint2(v0, v1);
      }
    }
  } else {
    // ---- ya -> bf16 conversion part (256 blocks, 262144 uint4 chunks) ----
    const int id = (b - 256) * 256 + tid;  // 0..65535
    const float4* src = (const float4*)ya;
    uint4* dst = (uint4*)yabf;
#pragma unroll
    for (int u = 0; u < 4; ++u) {
      int d = id + u * 65536;
      float4 a = src[d * 2];
      float4 c = src[d * 2 + 1];
      uint4 o = { f2bf2(a.x, a.y), f2bf2(a.z, a.w),
                  f2bf2(c.x, c.y), f2bf2(c.z, c.w) };
      dst[d] = o;
    }
    if (b == 511) {
      float4 z = {0.f, 0.f, 0.f, 0.f};
      float4* sv = (float4*)svec;
#pragma unroll
      for (int u = 0; u < 8; ++u) sv[u * 256 + tid] = z;
    }
  }
}

// ---------------------------------------------------------------------------
// k2: s[i] += sum_j sigmoid( ya[i] . proj[j] )
// 64-col tiles: 8 sync events instead of 16 (halve lockstep cost), 2 x 32 KB
// LDS double buffer, 2 blocks/CU. Ordering per tile (proven race-free):
//   s_waitcnt vmcnt(0)  [my stage loads for tile t done; they had a full
//                        compute phase in flight -> near-free]
//   s_barrier           [ALL waves' tile-t loads landed; buf of t-1 free]
//   stage t+1           [8 global_load_lds/thread, overlaps whole compute]
//   compute t           [4 col16 phases; sigmoid of phase p-1 software-
//                        pipelined behind MFMAs of phase p (accA/accB)]
// ---------------------------------------------------------------------------
__global__ __launch_bounds__(256, 2) void k2_score(
    const unsigned short* __restrict__ yabf, const unsigned short* __restrict__ PX,
    float* __restrict__ svec)
{
  __shared__ __align__(16) unsigned short bs[2][16384]; // 2 x 32 KB
  const int tid  = threadIdx.x;
  const int lane = tid & 63;
  const int w    = tid >> 6;
  const int quad = lane >> 4;
  const int l15  = lane & 15;

  // XCD swizzle: bid = k*8 + xcd -> XCD 'xcd' sees only col-slices {2xcd, 2xcd+1}
  const int bid = blockIdx.x;          // 0..511
  const int xcd = bid & 7;
  const int k   = bid >> 3;            // 0..63
  const int by  = xcd * 2 + (k >> 5);  // 0..15
  const int bx  = k & 31;              // 0..31

  const int rbase = bx * 256 + w * 64;
  const int cg16  = by * 32;           // col16-group base (512 cols)

  const unsigned short* psrc = PX + (size_t)cg16 * 4096; // this block's 256 KB

#define STAGE(B, T)                                                          \
  do {                                                                       \
    const unsigned short* _src = psrc + (size_t)(T) * 16384;                 \
    unsigned short* _dst = &bs[(B)][0];                                      \
    _Pragma("unroll")                                                        \
    for (int p = 0; p < 8; ++p) {                                            \
      int c = p * 256 + tid;                                                 \
      __builtin_amdgcn_global_load_lds(                                      \
          (const __attribute__((address_space(1))) unsigned int*)(const void*)(_src + c * 8), \
          (__attribute__((address_space(3))) unsigned int*)(void*)(_dst + c * 8), \
          16, 0, 0);                                                         \
    }                                                                        \
  } while (0)

  // stage tile 0 first so its loads are oldest in the FIFO
  STAGE(0, 0);

  // A-frags: 64 ya rows per wave, direct bf16 16B loads (32 dwordx4/thread)
  frag_u A[4][8];
#pragma unroll
  for (int g = 0; g < 4; ++g) {
    const unsigned short* src = yabf + (size_t)(rbase + g * 16 + l15) * HDIM;
#pragma unroll
    for (int kb = 0; kb < 8; ++kb)
      A[g][kb].v = *(const bf16x8*)&src[kb * 32 + quad * 8];
  }

  float rs[4][4] = {{0.f,0.f,0.f,0.f},{0.f,0.f,0.f,0.f},
                    {0.f,0.f,0.f,0.f},{0.f,0.f,0.f,0.f}};

#define MFMA_PHASE(ACC, BUF, P)                                              \
  do {                                                                       \
    _Pragma("unroll")                                                        \
    for (int g = 0; g < 4; ++g) ACC[g] = (f32x4){0.f, 0.f, 0.f, 0.f};        \
    __builtin_amdgcn_s_setprio(1);                                           \
    _Pragma("unroll")                                                        \
    for (int kb = 0; kb < 8; ++kb) {                                         \
      bf16x8 bfrag = *(const bf16x8*)&BUF[(P) * 4096 + kb * 512 + lane * 8]; \
      _Pragma("unroll")                                                      \
      for (int g = 0; g < 4; ++g)                                            \
        ACC[g] = __builtin_amdgcn_mfma_f32_16x16x32_bf16(                    \
            A[g][kb].v, bfrag, ACC[g], 0, 0, 0);                             \
    }                                                                        \
    __builtin_amdgcn_s_setprio(0);                                           \
  } while (0)

#define SIG(ACC)                                                             \
  do {                                                                       \
    _Pragma("unroll")                                                        \
    for (int g = 0; g < 4; ++g)                                              \
      _Pragma("unroll")                                                      \
      for (int r = 0; r < 4; ++r)                                            \
        rs[g][r] += sigmoidf_fast(ACC[g][r]);                                \
  } while (0)

  for (int t = 0; t < 8; ++t) {        // 8 tiles x 64 cols = 512 cols
    asm volatile("s_waitcnt vmcnt(0)" ::: "memory"); // my tile-t loads done (near-free)
    asm volatile("s_barrier" ::: "memory");          // everyone's tile-t loads done
    if (t < 7)
      STAGE((t + 1) & 1, t + 1);       // overlaps the whole compute phase below

    const unsigned short* buf = &bs[t & 1][0];
    f32x4 accA[4], accB[4];
    // software-pipelined: sigmoid of phase p-1 runs behind MFMAs of phase p
    MFMA_PHASE(accA, buf, 0);
    MFMA_PHASE(accB, buf, 1);
    SIG(accA);
    MFMA_PHASE(accA, buf, 2);
    SIG(accB);
    MFMA_PHASE(accB, buf, 3);
    SIG(accA);
    SIG(accB);
  }
#undef STAGE
#undef MFMA_PHASE
#undef SIG

  // reduce over the 16 col-lanes within each quad group
#pragma unroll
  for (int off = 1; off < 16; off <<= 1)
#pragma unroll
    for (int g = 0; g < 4; ++g)
#pragma unroll
      for (int r = 0; r < 4; ++r)
        rs[g][r] += __shfl_xor(rs[g][r], off, 64);

  if (l15 == 0) {
#pragma unroll
    for (int g = 0; g < 4; ++g)
#pragma unroll
      for (int r = 0; r < 4; ++r)
        atomicAdd(&svec[rbase + g * 16 + quad * 4 + r], rs[g][r]);
  }
}

// ---------------------------------------------------------------------------
// k3: out[i][k] = s[i] / 256
// ---------------------------------------------------------------------------
__global__ __launch_bounds__(256) void k3_bcast(
    const float* __restrict__ svec, float* __restrict__ out)
{
  int idx = blockIdx.x * 256 + threadIdx.x;
  int row = idx >> 6;
  float v = svec[row] * (1.0f / 256.0f);
  float4 o = {v, v, v, v};
  ((float4*)out)[idx] = o;
}

extern "C" void kernel_launch(void* const* d_in, const int* in_sizes, int n_in,
                              void* d_out, int out_size, void* d_ws, size_t ws_size,
                              hipStream_t stream) {
  (void)in_sizes; (void)n_in; (void)out_size;
  const float* ya = (const float*)d_in[0];
  const float* yb = (const float*)d_in[1];
  const float* W  = (const float*)d_in[2];
  const float* bv = (const float*)d_in[3];
  float* out = (float*)d_out;

  char* ws = (char*)d_ws;
  unsigned short *PX, *yabf;
  float* svec;
  const size_t need = (8ull << 20) + (32ull << 10);
  if (ws_size >= need) {
    PX   = (unsigned short*)ws;
    yabf = (unsigned short*)(ws + (4 << 20));
    svec = (float*)(ws + (8 << 20));
  } else {
    PX   = (unsigned short*)d_out;                 // aliases out; k3 rewrites all
    yabf = (unsigned short*)((char*)d_out + (4 << 20));
    svec = (float*)ws;
  }

  k1_fused<<<512, 256, 0, stream>>>(ya, yb, W, bv, yabf, PX, svec);
  k2_score<<<512, 256, 0, stream>>>(yabf, PX, svec);
  k3_bcast<<<2048, 256, 0, stream>>>(svec, out);
}